// Round 11
// baseline (60.686 us; speedup 1.0000x reference)
//
#include <hip/hip_runtime.h>
#include <hip/hip_bf16.h>

// Problem constants (fixed by setup_inputs): B=4, S=8192, D=1024, E=64, top_k=1
#define NB 4
#define NS 8192
#define ND 1024
#define NE 64
#define NM (NB * NS)          // 32768 tokens
#define CAPACITY 640

#define BM 32                 // tokens per k1 block == hist chunk size
#define BK 32                 // K-tile == one MFMA k-slice
#define NKT (ND / BK)         // 32 K-tiles
#define NBLK (NM / BM)        // 1024 blocks -> 4/CU, all resident
#define C32PB (NS / BM)       // 256 32-chunks per batch

#define OCH 64                // tokens per output block
#define NOB (NM / OCH)        // 512 output blocks

typedef short short8 __attribute__((ext_vector_type(8)));
typedef float f32x4 __attribute__((ext_vector_type(4)));

#define GLOAD16(g, l)                                                          \
    __builtin_amdgcn_global_load_lds(                                          \
        (const __attribute__((address_space(1))) void*)(g),                    \
        (__attribute__((address_space(3))) void*)(l), 16, 0, 0)

// ---------------------------------------------------------------------------
// K1: async-DMA double-buffered bf16x3-split MFMA GEMM + fused softmax-top1.
// vs r10: tile granularity halved (BM=32, BK=32, 128 threads, grid 1024 ->
// 4 blocks/CU) for 4 independent stage/compute pipelines per CU. K-slice
// sequence and split math bitwise-identical to r5-r10 => same logits.
// Per tile: 12 gload16 units (x rows 0-31 = 4 KB, W rows 0-63 = 8 KB),
// 6 per wave, counted vmcnt(6). LDS 24 KB: xs[2]x4K | ws[2]x8K; sLog reuses.
// Source-swizzle (unit ^ row&7) on the global address, un-XOR on ds_read
// (rule #21). Loop: stage(kt+1) -> vmcnt(6) -> s_barrier -> compute(kt)
// -> s_barrier. C/D layout (m89/m91): col=lane&15, row=(lane>>4)*4+reg.
// ---------------------------------------------------------------------------
__global__ __launch_bounds__(128, 4) void k1_mfma(const float* __restrict__ x,
                                                  const float* __restrict__ W,
                                                  float* __restrict__ logits,
                                                  int* __restrict__ idx_ws,
                                                  float* __restrict__ prob_ws,
                                                  int* __restrict__ hist)
{
    // xs0 [0,4K) | xs1 [4K,8K) | ws0 [8K,16K) | ws1 [16K,24K); sLog = [0,8K)
    __shared__ char SL[24576];
    __shared__ int lh[NE];

    const int tid = threadIdx.x;
    const int lane = tid & 63;
    const int wv = tid >> 6;          // 0..1
    const int lr = lane & 15;
    const int kq = lane >> 4;
    const int tok0 = blockIdx.x * BM;

    if (tid < NE) lh[tid] = 0;

    f32x4 acc[4];
#pragma unroll
    for (int j = 0; j < 4; ++j) acc[j] = (f32x4){0.f, 0.f, 0.f, 0.f};

    // ---- async staging: 12 gload16 units per tile, 6 per wave -------------
    // unit u<4: x rows [u*8, u*8+8); u>=4: W rows [(u-4)*8, +8).
    // Each unit: lane l -> row base + (l>>3), source 16B-slot (l&7)^(row&7),
    // LDS lands row-linear (dst + l*16).
    auto stage = [&](int kt, int b) {
        const int k0 = kt * BK;
        const int lrow8 = lane >> 3;     // 0..7
        const int uslot = lane & 7;
        const int u0 = wv * 6;
#pragma unroll
        for (int q = 0; q < 6; ++q) {
            const int u = u0 + q;
            if (u < 4) {
                const int r = u * 8 + lrow8;
                const int su = uslot ^ (r & 7);
                const float* g = x + (size_t)(tok0 + r) * ND + k0 + su * 4;
                GLOAD16(g, SL + b * 4096 + u * 1024);
            } else {
                const int r = (u - 4) * 8 + lrow8;
                const int su = uslot ^ (r & 7);
                const float* g = W + (size_t)r * ND + k0 + su * 4;
                GLOAD16(g, SL + 8192 + b * 8192 + (u - 4) * 1024);
            }
        }
    };

    // ---- compute one K-tile (one MFMA k-slice) from buffer b --------------
    auto compute = [&](int b) {
        const float* xsb = (const float*)(SL + b * 4096);          // [32][32] f32
        const float* wsb = (const float*)(SL + 8192 + b * 8192);   // [64][32] f32
        const int arow = wv * 16 + lr;
        const int l7 = lr & 7;
        const int su = kq * 2;
        f32x4 a0 = *(const f32x4*)&xsb[arow * 32 + ((su)     ^ l7) * 4];
        f32x4 a1 = *(const f32x4*)&xsb[arow * 32 + ((su + 1) ^ l7) * 4];
        float f[8] = {a0[0], a0[1], a0[2], a0[3], a1[0], a1[1], a1[2], a1[3]};
        short8 ah, al;
#pragma unroll
        for (int c = 0; c < 8; ++c) {
            unsigned int u = __builtin_bit_cast(unsigned int, f[c]);
            ah[c] = (short)(u >> 16);                         // trunc hi (as r5-r10)
            float fhi = __builtin_bit_cast(float, u & 0xFFFF0000u);
            __hip_bfloat16 lb = __float2bfloat16(f[c] - fhi); // RNE lo (as r5-r10)
            al[c] = __builtin_bit_cast(short, lb);
        }
#pragma unroll
        for (int j = 0; j < 4; ++j) {
            const int erow = j * 16 + lr;                     // erow&7 == lr&7
            f32x4 w0 = *(const f32x4*)&wsb[erow * 32 + ((su)     ^ l7) * 4];
            f32x4 w1 = *(const f32x4*)&wsb[erow * 32 + ((su + 1) ^ l7) * 4];
            float g[8] = {w0[0], w0[1], w0[2], w0[3], w1[0], w1[1], w1[2], w1[3]};
            short8 bh, bl;
#pragma unroll
            for (int c = 0; c < 8; ++c) {
                __hip_bfloat16 hb = __float2bfloat16(g[c]);   // RNE hi (as r9/r10)
                float r = g[c] - __bfloat162float(hb);
                __hip_bfloat16 lb = __float2bfloat16(r);      // RNE lo
                bh[c] = __builtin_bit_cast(short, hb);
                bl[c] = __builtin_bit_cast(short, lb);
            }
            acc[j] = __builtin_amdgcn_mfma_f32_16x16x32_bf16(ah, bh, acc[j], 0, 0, 0);
            acc[j] = __builtin_amdgcn_mfma_f32_16x16x32_bf16(ah, bl, acc[j], 0, 0, 0);
            acc[j] = __builtin_amdgcn_mfma_f32_16x16x32_bf16(al, bh, acc[j], 0, 0, 0);
        }
    };

    // ---- main loop: counted-vmcnt 2-phase pipeline ----
    stage(0, 0);
#pragma unroll
    for (int kt = 0; kt < NKT; ++kt) {
        const int b = kt & 1;
        if (kt + 1 < NKT) {
            stage(kt + 1, b ^ 1);
            asm volatile("s_waitcnt vmcnt(6)" ::: "memory");   // tile kt done
        } else {
            asm volatile("s_waitcnt vmcnt(0)" ::: "memory");
        }
        __builtin_amdgcn_s_barrier();
        __builtin_amdgcn_sched_barrier(0);
        compute(b);
        __builtin_amdgcn_sched_barrier(0);
        __builtin_amdgcn_s_barrier();          // reads done; kt+2 may overwrite b
    }

    __syncthreads();   // full fence before reusing xs region as sLog

    float* sLog = (float*)SL;

    // ---- fused epilogue: per-token softmax top-1 (each wave: its 16 tokens)
#pragma unroll
    for (int r = 0; r < 4; ++r) {
        const int tl = wv * 16 + kq * 4 + r;   // token local to block (0..31)
        float val[4];
#pragma unroll
        for (int j = 0; j < 4; ++j) val[j] = acc[j][r];

        // local argmax over j (ascending j + strict > keeps lowest expert)
        float m = val[0];
        int mi = lr;
#pragma unroll
        for (int j = 1; j < 4; ++j) {
            if (val[j] > m) { m = val[j]; mi = j * 16 + lr; }
        }
        // butterfly across the 16 lanes of this fragment-row group
#pragma unroll
        for (int off = 1; off < 16; off <<= 1) {
            float m2 = __shfl_xor(m, off);
            int mi2 = __shfl_xor(mi, off);
            if (m2 > m || (m2 == m && mi2 < mi)) { m = m2; mi = mi2; }
        }
        // softmax denominator
        float s = 0.0f;
#pragma unroll
        for (int j = 0; j < 4; ++j) s += __expf(val[j] - m);
#pragma unroll
        for (int off = 1; off < 16; off <<= 1) s += __shfl_xor(s, off);

        // stage logits in LDS for dense write
#pragma unroll
        for (int j = 0; j < 4; ++j) sLog[tl * NE + j * 16 + lr] = val[j];
        if (lr == 0) {
            idx_ws[tok0 + tl] = mi;
            prob_ws[tok0 + tl] = 1.0f / s;
            atomicAdd(&lh[mi], 1);
        }
    }
    __syncthreads();

    // dense logits write: 2048 floats = 4 passes x 128 thr x float4
    const size_t g0 = (size_t)tok0 * NE;
#pragma unroll
    for (int i = 0; i < 4; ++i) {
        const int fl = i * 512 + tid * 4;
        *(float4*)&logits[g0 + fl] = *(const float4*)&sLog[fl];
    }
    if (tid < NE) hist[blockIdx.x * NE + tid] = lh[tid];
}

// ---------------------------------------------------------------------------
// K2: output kernel (r7-proven accounting, 32-token hist chunks).
// One block per 64-token slab (512 blocks x 256 thr): base = 4-wave strided
// sum over the batch's preceding 2*s 32-chunks, ordered capacity rank
// (wave 0, lane = expert, INCLUSIVE <= CAPACITY), dense float4 e/p writes.
// ---------------------------------------------------------------------------
__global__ __launch_bounds__(256) void k_out(const int* __restrict__ idx_ws,
                                             const float* __restrict__ prob_ws,
                                             const int* __restrict__ hist,
                                             float* __restrict__ e_out,
                                             float* __restrict__ p_out)
{
    __shared__ int sMi[OCH];
    __shared__ float sPr[OCH];
    __shared__ int sAd[OCH];
    __shared__ int pp[4][NE];

    const int c = blockIdx.x;        // 0..511
    const int b = c >> 7;            // batch (128 slabs per batch)
    const int s = c & 127;           // slab within batch
    const int t0 = c * OCH;
    const int tid = threadIdx.x;
    const int lane = tid & 63;
    const int wv = tid >> 6;

    if (tid < OCH) {
        sMi[tid] = idx_ws[t0 + tid];
        sPr[tid] = prob_ws[t0 + tid];
    }

    // strided partial sums over the batch's preceding 2*s 32-chunks
    {
        int run = 0;
        const int* hrow = hist + (size_t)(b * C32PB) * NE + lane;
        const int n = 2 * s;
        for (int i = wv; i < n; i += 4) run += hrow[i * NE];
        pp[wv][lane] = run;
    }
    __syncthreads();

    if (wv == 0) {
        int run = pp[0][lane] + pp[1][lane] + pp[2][lane] + pp[3][lane];
        for (int j = 0; j < OCH; ++j) {
            if (sMi[j] == lane) { ++run; sAd[j] = (run <= CAPACITY) ? 1 : 0; }
        }
    }
    __syncthreads();

    // dense e/p writes: 4096 floats each = 4 passes x 256 thr x float4
    const size_t g0 = (size_t)t0 * NE;
#pragma unroll
    for (int i = 0; i < 4; ++i) {
        const int fl = i * 1024 + tid * 4;
        const int t = fl >> 6;
        const int e0 = fl & 63;
        const int mi = sMi[t];
        const float pr = sPr[t];
        const int ad = sAd[t];
        float4 ev, pv;
        float* evp = &ev.x;
        float* pvp = &pv.x;
#pragma unroll
        for (int cc = 0; cc < 4; ++cc) {
            const bool hit = (mi == e0 + cc) && ad;
            evp[cc] = hit ? 1.0f : 0.0f;
            pvp[cc] = hit ? pr : 0.0f;
        }
        *(float4*)&e_out[g0 + fl] = ev;
        *(float4*)&p_out[g0 + fl] = pv;
    }
}

// ---------------------------------------------------------------------------
extern "C" void kernel_launch(void* const* d_in, const int* in_sizes, int n_in,
                              void* d_out, int out_size, void* d_ws, size_t ws_size,
                              hipStream_t stream)
{
    const float* x = (const float*)d_in[0];   // [B,S,D] fp32
    const float* W = (const float*)d_in[1];   // [E,D] fp32
    // d_in[2] = top_k (==1), ignored

    float* out = (float*)d_out;
    float* e_out = out;                          // expert_indices as 0.0/1.0
    float* p_out = out + (size_t)NM * NE;        // router_probs
    float* logits = out + 2 * (size_t)NM * NE;   // logits

    char* ws = (char*)d_ws;
    int* idx_ws    = (int*)ws;                                   // 128 KB
    float* prob_ws = (float*)(ws + (size_t)NM * 4);              // 128 KB
    int* hist      = (int*)(ws + (size_t)NM * 8);                // 1024*64*4 = 256 KB

    k1_mfma<<<NBLK, 128, 0, stream>>>(x, W, logits, idx_ws, prob_ws, hist);
    k_out<<<NOB, 256, 0, stream>>>(idx_ws, prob_ws, hist, e_out, p_out);
}